// Round 3
// baseline (2291.932 us; speedup 1.0000x reference)
//
#include <hip/hip_runtime.h>

// GatedLinearAttention, all-fp32 (per reference dtypes).
// B=2, S=8192, H=1024, NH=16, dk=dv=64, T=16384 tokens.
// Pipeline (ws ~113 MB):
//   K1: kb = elu(h@Wk)+1          fp32 [16384][1024]   (tiled VALU GEMM)
//   K1b: ksum two-stage deterministic
//   for chunk c in 0..3 (4096 tokens):
//     K2c: qc=elu(h@Wq)+1, vc=h@Wv, gc=h@Wg  (one GEMM grid, by selects weight)
//     K3c: per-token z, two-pass LayerNorm, SiLU gate -> overwrite kb row (z)
//   K4: out = z @ Wo  fp32

#define HDIM  1024
#define T_TOK 16384
#define CROWS 4096

// ---------------- fp32 tiled GEMM: 128x128 tile, BK=16, 256 threads ----------------
// A [M][K] row-major, B [K][1024] row-major (weights are natively [k][n] - no transpose).
// VAR 0: D0 = elu(A@B0)+1          grid (M/128, 8)
// VAR 1: D0=elu(A@B0)+1, D1=A@B1, D2=A@B2 selected by by>>3   grid (M/128, 24)
// VAR 2: D0 = A@B0                 grid (M/128, 8)
template <int VAR>
__global__ __launch_bounds__(256)
void gemm_f32(const float* __restrict__ A,
              const float* __restrict__ B0, const float* __restrict__ B1,
              const float* __restrict__ B2,
              float* __restrict__ D0, float* __restrict__ D1, float* __restrict__ D2,
              int K) {
    __shared__ float As[16][132];  // As[k][m], padded
    __shared__ float Bs[16][132];  // Bs[k][n]
    const int tid = threadIdx.x;
    const int bx = blockIdx.x, by = blockIdx.y;

    const float* B;
    float* D;
    int n0;
    bool act;
    if (VAR == 1) {
        const int wsel = by >> 3;  // uniform per block: 0=q,1=v,2=g
        B = (wsel == 0) ? B0 : (wsel == 1) ? B1 : B2;
        D = (wsel == 0) ? D0 : (wsel == 1) ? D1 : D2;
        n0 = (by & 7) * 128;
        act = (wsel == 0);
    } else {
        B = B0; D = D0; n0 = by * 128; act = (VAR == 0);
    }

    const size_t rowbase = (size_t)bx * 128;
    const int tm = tid & 15, tn = tid >> 4;

    float acc[8][8];
#pragma unroll
    for (int i = 0; i < 8; ++i)
#pragma unroll
        for (int j = 0; j < 8; ++j) acc[i][j] = 0.0f;

    for (int k0 = 0; k0 < K; k0 += 16) {
        float4 a[2], b[2];
#pragma unroll
        for (int s = 0; s < 2; ++s) {
            const int id = tid + s * 256;
            const int arow = id >> 2, akc = (id & 3) << 2;
            a[s] = *(const float4*)(A + (rowbase + arow) * (size_t)K + k0 + akc);
            const int brow = id >> 5, bc = (id & 31) << 2;
            b[s] = *(const float4*)(B + (size_t)(k0 + brow) * HDIM + n0 + bc);
        }
        __syncthreads();
#pragma unroll
        for (int s = 0; s < 2; ++s) {
            const int id = tid + s * 256;
            const int arow = id >> 2, akc = (id & 3) << 2;
            As[akc + 0][arow] = a[s].x;
            As[akc + 1][arow] = a[s].y;
            As[akc + 2][arow] = a[s].z;
            As[akc + 3][arow] = a[s].w;
            const int brow = id >> 5, bc = (id & 31) << 2;
            *(float4*)&Bs[brow][bc] = b[s];
        }
        __syncthreads();
#pragma unroll
        for (int kk = 0; kk < 16; ++kk) {
            const float4 a0 = *(const float4*)&As[kk][tm * 4];
            const float4 a1 = *(const float4*)&As[kk][64 + tm * 4];
            const float4 b0 = *(const float4*)&Bs[kk][tn * 4];
            const float4 b1 = *(const float4*)&Bs[kk][64 + tn * 4];
            const float am[8] = {a0.x, a0.y, a0.z, a0.w, a1.x, a1.y, a1.z, a1.w};
            const float bn[8] = {b0.x, b0.y, b0.z, b0.w, b1.x, b1.y, b1.z, b1.w};
#pragma unroll
            for (int i = 0; i < 8; ++i)
#pragma unroll
                for (int j = 0; j < 8; ++j) acc[i][j] += am[i] * bn[j];
        }
    }

#pragma unroll
    for (int i = 0; i < 8; ++i) {
        const int m = (i < 4) ? (tm * 4 + i) : (64 + tm * 4 + (i - 4));
        float vlo[4], vhi[4];
#pragma unroll
        for (int j = 0; j < 4; ++j) { vlo[j] = acc[i][j]; vhi[j] = acc[i][4 + j]; }
        if (act) {
#pragma unroll
            for (int j = 0; j < 4; ++j) {
                vlo[j] = (vlo[j] > 0.0f) ? (vlo[j] + 1.0f) : (expm1f(vlo[j]) + 1.0f);
                vhi[j] = (vhi[j] > 0.0f) ? (vhi[j] + 1.0f) : (expm1f(vhi[j]) + 1.0f);
            }
        }
        float4 lo = {vlo[0], vlo[1], vlo[2], vlo[3]};
        float4 hi = {vhi[0], vhi[1], vhi[2], vhi[3]};
        *(float4*)(D + (rowbase + m) * (size_t)HDIM + n0 + tn * 4) = lo;
        *(float4*)(D + (rowbase + m) * (size_t)HDIM + n0 + 64 + tn * 4) = hi;
    }
}

// ---------------- ksum: deterministic two-stage ----------------
__global__ void ksum_partial(const float* __restrict__ kf, float* __restrict__ partial) {
    const int rg = blockIdx.x;  // 256 groups of 64 rows
    const int tid = threadIdx.x;
    const float4* p = (const float4*)(kf + (size_t)rg * 64 * HDIM) + tid;
    float4 s = {0.f, 0.f, 0.f, 0.f};
    for (int r = 0; r < 64; ++r) {
        float4 x = p[(size_t)r * (HDIM / 4)];
        s.x += x.x; s.y += x.y; s.z += x.z; s.w += x.w;
    }
    ((float4*)(partial + (size_t)rg * HDIM))[tid] = s;
}
__global__ void ksum_reduce(const float* __restrict__ partial, float* __restrict__ ksum) {
    const int b = blockIdx.y;
    const int c = blockIdx.x * 256 + threadIdx.x;
    float s = 0.f;
    const float* p = partial + (size_t)b * 128 * HDIM + c;
    for (int rg = 0; rg < 128; ++rg) s += p[(size_t)rg * HDIM];
    ksum[b * HDIM + c] = s;
}

// ---------------- per-token: z, two-pass LayerNorm, SiLU gate ----------------
// Reads k[t] from kz, writes gated z over the same row (each thread's own 16B).
__global__ __launch_bounds__(256)
void token_f32(const float* __restrict__ qd, const float* __restrict__ vd,
               const float* __restrict__ gd, float* kz,
               const float* __restrict__ ksum,
               const float* __restrict__ gamma, const float* __restrict__ beta,
               int chunk_base) {
    const int tl = blockIdx.x;
    const int t = chunk_base + tl;
    const int b = t >> 13;
    const int tid = threadIdx.x;

    const float4 q = ((const float4*)(qd + (size_t)tl * HDIM))[tid];
    const float4 k = ((const float4*)(kz + (size_t)t * HDIM))[tid];
    const float4 v = ((const float4*)(vd + (size_t)tl * HDIM))[tid];
    const float4 ks = ((const float4*)(ksum + (size_t)b * HDIM))[tid];

    float qk = q.x * k.x + q.y * k.y + q.z * k.z + q.w * k.w;
    float nm = q.x * ks.x + q.y * ks.y + q.z * ks.z + q.w * ks.w;
#pragma unroll
    for (int off = 1; off < 16; off <<= 1) {  // per-head reduce (16 lanes/head)
        qk += __shfl_xor(qk, off, 64);
        nm += __shfl_xor(nm, off, 64);
    }
    const float sc = qk / (nm + 1e-6f);
    float z[4] = {v.x * sc, v.y * sc, v.z * sc, v.w * sc};

    __shared__ float red[8];
    const int wv = tid >> 6, lane = tid & 63;

    // pass 1: mean
    float s1 = z[0] + z[1] + z[2] + z[3];
#pragma unroll
    for (int off = 1; off < 64; off <<= 1) s1 += __shfl_xor(s1, off, 64);
    if (lane == 0) red[wv] = s1;
    __syncthreads();
    const float mu = (red[0] + red[1] + red[2] + red[3]) * (1.0f / 1024.0f);

    // pass 2: variance of (z - mu)
    float d[4] = {z[0] - mu, z[1] - mu, z[2] - mu, z[3] - mu};
    float s2 = d[0] * d[0] + d[1] * d[1] + d[2] * d[2] + d[3] * d[3];
#pragma unroll
    for (int off = 1; off < 64; off <<= 1) s2 += __shfl_xor(s2, off, 64);
    __syncthreads();  // ensure all reads of red (mu) done before rewrite
    if (lane == 0) red[4 + wv] = s2;
    __syncthreads();
    const float var = (red[4] + red[5] + red[6] + red[7]) * (1.0f / 1024.0f);
    const float rstd = rsqrtf(var + 1e-5f);

    const float4 gm = ((const float4*)gamma)[tid];
    const float4 bt = ((const float4*)beta)[tid];
    const float4 g = ((const float4*)(gd + (size_t)tl * HDIM))[tid];
    const float gv[4] = {g.x, g.y, g.z, g.w};
    const float gmv[4] = {gm.x, gm.y, gm.z, gm.w};
    const float btv[4] = {bt.x, bt.y, bt.z, bt.w};

    float o[4];
#pragma unroll
    for (int c = 0; c < 4; ++c) {
        const float zn = d[c] * rstd * gmv[c] + btv[c];
        const float sg = gv[c] / (1.0f + expf(-gv[c]));  // silu
        o[c] = zn * sg;
    }
    float4 u = {o[0], o[1], o[2], o[3]};
    ((float4*)(kz + (size_t)t * HDIM))[tid] = u;  // overwrite own 16B of k with z
}

// ---------------- launcher ----------------
extern "C" void kernel_launch(void* const* d_in, const int* in_sizes, int n_in,
                              void* d_out, int out_size, void* d_ws, size_t ws_size,
                              hipStream_t stream) {
    const float* hidden = (const float*)d_in[0];
    const float* Wq = (const float*)d_in[1];
    const float* Wk = (const float*)d_in[2];
    const float* Wv = (const float*)d_in[3];
    const float* Wg = (const float*)d_in[4];
    const float* Wo = (const float*)d_in[5];
    const float* gamma = (const float*)d_in[6];
    const float* beta = (const float*)d_in[7];

    // workspace (~113.3 MB)
    const size_t TH = (size_t)T_TOK * HDIM;
    const size_t CH = (size_t)CROWS * HDIM;
    float* kb = (float*)d_ws;        // 64 MB, later aliased by gated z
    float* qc = kb + TH;             // 16 MB
    float* vc = qc + CH;             // 16 MB
    float* gc = vc + CH;             // 16 MB
    float* partial = gc + CH;        // 1 MB
    float* ksum = partial + (size_t)256 * HDIM;  // 8 KB

    // k = elu(h@Wk)+1
    gemm_f32<0><<<dim3(128, 8), 256, 0, stream>>>(hidden, Wk, nullptr, nullptr,
                                                  kb, nullptr, nullptr, HDIM);
    // ksum (deterministic)
    ksum_partial<<<dim3(256), 256, 0, stream>>>(kb, partial);
    ksum_reduce<<<dim3(4, 2), 256, 0, stream>>>(partial, ksum);

    // 4 chunks of 4096 tokens
    for (int c = 0; c < 4; ++c) {
        const float* Ac = hidden + (size_t)c * CH;
        gemm_f32<1><<<dim3(32, 24), 256, 0, stream>>>(Ac, Wq, Wv, Wg,
                                                      qc, vc, gc, HDIM);
        token_f32<<<dim3(CROWS), 256, 0, stream>>>(qc, vc, gc, kb, ksum,
                                                   gamma, beta, c * CROWS);
    }

    // out = z @ Wo
    gemm_f32<2><<<dim3(128, 8), 256, 0, stream>>>(kb, Wo, nullptr, nullptr,
                                                  (float*)d_out, nullptr, nullptr, HDIM);
}

// Round 4
// 1573.422 us; speedup vs baseline: 1.4567x; 1.4567x over previous
//
#include <hip/hip_runtime.h>

// GatedLinearAttention, fp32 I/O, split-bf16 MFMA GEMMs.
// B=2, S=8192, H=1024, NH=16, dk=dv=64, T=16384 tokens.
//
// GEMM trick: fp32 A,B each split as x = hi + lo (both bf16).
//   A@B ~= Ahi@Bhi + Alo@Bhi + Ahi@Blo   (drop lo*lo, rel err ~1e-5)
// Weights pre-transposed+split once: WT2[n][0..1023]=hi(k), [1024..2047]=lo(k).
// Activations split on the fly during global->LDS staging (fp32 read, bf16x2 store).
//
// Pipeline (ws ~109 MB):
//   W: split/transpose Wk,Wq,Wv,Wg,Wo -> WT2[5]
//   K1: kb = elu(h@Wk)+1  fp32 [16384][1024]      (MFMA split GEMM)
//   K1b: ksum two-stage deterministic
//   for chunk c in 0..7 (2048 tokens):
//     K2c: qc=elu(h@Wq)+1, vc=h@Wv, gc=h@Wg      (MFMA split GEMM, by selects W)
//     K3c: per-token z, LayerNorm, SiLU gate -> overwrite kb row with z (fp32)
//   K4: out = z @ Wo                              (MFMA split GEMM)

typedef unsigned short ushort_t;
typedef unsigned int uint_t;

using short8  = __attribute__((ext_vector_type(8))) short;
using floatx4 = __attribute__((ext_vector_type(4))) float;

#define HDIM  1024
#define T_TOK 16384
#define CROWS 2048

__device__ __forceinline__ ushort_t f2bf(float f) {
    uint_t u = __builtin_bit_cast(uint_t, f);
    u = (u + 0x7fff + ((u >> 16) & 1)) >> 16;  // RNE
    return (ushort_t)u;
}
__device__ __forceinline__ float bf2f(ushort_t h) {
    uint_t u = ((uint_t)h) << 16;
    return __builtin_bit_cast(float, u);
}
__device__ __forceinline__ void split2(float f, ushort_t& hi, ushort_t& lo) {
    hi = f2bf(f);
    lo = f2bf(f - bf2f(hi));
}

// ---------------- weight split+transpose: W[k][n] fp32 -> WT2[n][2048] bf16 ----------------
// blockIdx.z = 0..4 selects weight (k,q,v,g,o). WT2 row n: [0..1023]=hi(k), [1024..2047]=lo(k).
__global__ void split_w(const float* __restrict__ W0, const float* __restrict__ W1,
                        const float* __restrict__ W2, const float* __restrict__ W3,
                        const float* __restrict__ W4, ushort_t* __restrict__ WT2) {
    __shared__ float tile[32][33];
    const int z = blockIdx.z;
    const float* W = (z == 0) ? W0 : (z == 1) ? W1 : (z == 2) ? W2 : (z == 3) ? W3 : W4;
    ushort_t* dst = WT2 + (size_t)z * HDIM * 2048;
    const int n0 = blockIdx.x * 32, k0 = blockIdx.y * 32;
    const int tx = threadIdx.x & 31, ty0 = threadIdx.x >> 5;
#pragma unroll
    for (int s = 0; s < 4; ++s) {
        int ty = ty0 + 8 * s;
        tile[ty][tx] = W[(size_t)(k0 + ty) * HDIM + n0 + tx];
    }
    __syncthreads();
#pragma unroll
    for (int s = 0; s < 4; ++s) {
        int ty = ty0 + 8 * s;  // n-offset
        float v = tile[tx][ty];  // W[k0+tx][n0+ty]
        ushort_t hi, lo;
        split2(v, hi, lo);
        dst[(size_t)(n0 + ty) * 2048 + k0 + tx] = hi;
        dst[(size_t)(n0 + ty) * 2048 + 1024 + k0 + tx] = lo;
    }
}

// ---------------- split-bf16 MFMA GEMM: 128x128 tile, BK=64, 256 threads ----------------
// A [M][K] fp32 row-major (split on the fly). Bt = WT2-style [1024][2048] bf16.
// VAR 0: D0 = elu(A@B)+1, grid (M/128, 8), B=B0
// VAR 1: grid (M/128, 24): wsel=by>>3: 0->D0=elu(A@Bq)+1, 1->D1=A@Bv, 2->D2=A@Bg
// VAR 2: D0 = A@B, grid (M/128, 8)
template <int VAR>
__global__ __launch_bounds__(256, 2)
void gemm_split(const float* __restrict__ A,
                const ushort_t* __restrict__ B0, const ushort_t* __restrict__ B1,
                const ushort_t* __restrict__ B2,
                float* __restrict__ D0, float* __restrict__ D1, float* __restrict__ D2,
                int K) {
    __shared__ ushort_t Ah[128 * 72];
    __shared__ ushort_t Al[128 * 72];
    __shared__ ushort_t Bh[128 * 72];
    __shared__ ushort_t Bl[128 * 72];

    const int tid = threadIdx.x;
    const int bx = blockIdx.x, by = blockIdx.y;

    const ushort_t* Bt;
    float* D;
    int n0;
    bool act;
    if (VAR == 1) {
        const int wsel = by >> 3;
        Bt = (wsel == 0) ? B0 : (wsel == 1) ? B1 : B2;
        D = (wsel == 0) ? D0 : (wsel == 1) ? D1 : D2;
        n0 = (by & 7) * 128;
        act = (wsel == 0);
    } else {
        Bt = B0; D = D0; n0 = by * 128; act = (VAR == 0);
    }

    const int w = tid >> 6, lane = tid & 63;
    const int wm = w & 1, wn = w >> 1;
    const int lrow = lane & 15, lq = lane >> 4;

    // staging assignments: 2 threads per row
    const int srow = tid >> 1;          // 0..127
    const int shalf = (tid & 1) * 32;   // 0 or 32
    const float* Arow = A + (size_t)(bx * 128 + srow) * K;
    const ushort_t* Brow = Bt + (size_t)(n0 + srow) * 2048;

    floatx4 acc[4][4] = {};

    for (int k0 = 0; k0 < K; k0 += 64) {
        // ---- global loads ----
        float4 afr[8];
        uint4 bhr[4], blr[4];
#pragma unroll
        for (int g = 0; g < 4; ++g) {
            afr[2 * g]     = *(const float4*)(Arow + k0 + shalf + g * 8);
            afr[2 * g + 1] = *(const float4*)(Arow + k0 + shalf + g * 8 + 4);
            bhr[g] = *(const uint4*)(Brow + k0 + shalf + g * 8);
            blr[g] = *(const uint4*)(Brow + 1024 + k0 + shalf + g * 8);
        }
        __syncthreads();
        // ---- convert + stage to LDS ----
#pragma unroll
        for (int g = 0; g < 4; ++g) {
            ushort_t h[8], l[8];
            const float4 f0 = afr[2 * g], f1 = afr[2 * g + 1];
            split2(f0.x, h[0], l[0]); split2(f0.y, h[1], l[1]);
            split2(f0.z, h[2], l[2]); split2(f0.w, h[3], l[3]);
            split2(f1.x, h[4], l[4]); split2(f1.y, h[5], l[5]);
            split2(f1.z, h[6], l[6]); split2(f1.w, h[7], l[7]);
            uint4 hp, lp;
            hp.x = (uint_t)h[0] | ((uint_t)h[1] << 16);
            hp.y = (uint_t)h[2] | ((uint_t)h[3] << 16);
            hp.z = (uint_t)h[4] | ((uint_t)h[5] << 16);
            hp.w = (uint_t)h[6] | ((uint_t)h[7] << 16);
            lp.x = (uint_t)l[0] | ((uint_t)l[1] << 16);
            lp.y = (uint_t)l[2] | ((uint_t)l[3] << 16);
            lp.z = (uint_t)l[4] | ((uint_t)l[5] << 16);
            lp.w = (uint_t)l[6] | ((uint_t)l[7] << 16);
            *(uint4*)&Ah[srow * 72 + shalf + g * 8] = hp;
            *(uint4*)&Al[srow * 72 + shalf + g * 8] = lp;
            *(uint4*)&Bh[srow * 72 + shalf + g * 8] = bhr[g];
            *(uint4*)&Bl[srow * 72 + shalf + g * 8] = blr[g];
        }
        __syncthreads();
        // ---- MFMA: 3 split terms, A-hi frags reused for the B-lo term ----
#pragma unroll
        for (int kk = 0; kk < 64; kk += 32) {
            short8 ah[4], bh[4], xl[4];
#pragma unroll
            for (int i = 0; i < 4; ++i)
                ah[i] = *(const short8*)&Ah[(wm * 64 + i * 16 + lrow) * 72 + kk + lq * 8];
#pragma unroll
            for (int j = 0; j < 4; ++j)
                bh[j] = *(const short8*)&Bh[(wn * 64 + j * 16 + lrow) * 72 + kk + lq * 8];
#pragma unroll
            for (int i = 0; i < 4; ++i)
#pragma unroll
                for (int j = 0; j < 4; ++j)
                    acc[i][j] = __builtin_amdgcn_mfma_f32_16x16x32_bf16(ah[i], bh[j], acc[i][j], 0, 0, 0);
            // A-lo * B-hi
#pragma unroll
            for (int i = 0; i < 4; ++i)
                xl[i] = *(const short8*)&Al[(wm * 64 + i * 16 + lrow) * 72 + kk + lq * 8];
#pragma unroll
            for (int i = 0; i < 4; ++i)
#pragma unroll
                for (int j = 0; j < 4; ++j)
                    acc[i][j] = __builtin_amdgcn_mfma_f32_16x16x32_bf16(xl[i], bh[j], acc[i][j], 0, 0, 0);
            // A-hi * B-lo
#pragma unroll
            for (int j = 0; j < 4; ++j)
                xl[j] = *(const short8*)&Bl[(wn * 64 + j * 16 + lrow) * 72 + kk + lq * 8];
#pragma unroll
            for (int i = 0; i < 4; ++i)
#pragma unroll
                for (int j = 0; j < 4; ++j)
                    acc[i][j] = __builtin_amdgcn_mfma_f32_16x16x32_bf16(ah[i], xl[j], acc[i][j], 0, 0, 0);
        }
    }

    // C[row][col]: row = rowbase + i*16 + r, col = colbase + j*16 (m89/m91 layout)
    const int rowbase = bx * 128 + wm * 64 + lq * 4;
    const int colbase = n0 + wn * 64 + lrow;
#pragma unroll
    for (int i = 0; i < 4; ++i)
#pragma unroll
        for (int j = 0; j < 4; ++j) {
            const int col = colbase + j * 16;
#pragma unroll
            for (int r = 0; r < 4; ++r) {
                const int row = rowbase + i * 16 + r;
                float val = acc[i][j][r];
                if (act) val = (val > 0.0f) ? (val + 1.0f) : (expm1f(val) + 1.0f);
                D[(size_t)row * HDIM + col] = val;
            }
        }
}

// ---------------- ksum: deterministic two-stage ----------------
__global__ void ksum_partial(const float* __restrict__ kf, float* __restrict__ partial) {
    const int rg = blockIdx.x;  // 256 groups of 64 rows
    const int tid = threadIdx.x;
    const float4* p = (const float4*)(kf + (size_t)rg * 64 * HDIM) + tid;
    float4 s = {0.f, 0.f, 0.f, 0.f};
    for (int r = 0; r < 64; ++r) {
        float4 x = p[(size_t)r * (HDIM / 4)];
        s.x += x.x; s.y += x.y; s.z += x.z; s.w += x.w;
    }
    ((float4*)(partial + (size_t)rg * HDIM))[tid] = s;
}
__global__ void ksum_reduce(const float* __restrict__ partial, float* __restrict__ ksum) {
    const int b = blockIdx.y;
    const int c = blockIdx.x * 256 + threadIdx.x;
    float s = 0.f;
    const float* p = partial + (size_t)b * 128 * HDIM + c;
    for (int rg = 0; rg < 128; ++rg) s += p[(size_t)rg * HDIM];
    ksum[b * HDIM + c] = s;
}

// ---------------- per-token: z, two-pass LayerNorm, SiLU gate ----------------
__global__ __launch_bounds__(256)
void token_f32(const float* __restrict__ qd, const float* __restrict__ vd,
               const float* __restrict__ gd, float* kz,
               const float* __restrict__ ksum,
               const float* __restrict__ gamma, const float* __restrict__ beta,
               int chunk_base) {
    const int tl = blockIdx.x;
    const int t = chunk_base + tl;
    const int b = t >> 13;
    const int tid = threadIdx.x;

    const float4 q = ((const float4*)(qd + (size_t)tl * HDIM))[tid];
    const float4 k = ((const float4*)(kz + (size_t)t * HDIM))[tid];
    const float4 v = ((const float4*)(vd + (size_t)tl * HDIM))[tid];
    const float4 ks = ((const float4*)(ksum + (size_t)b * HDIM))[tid];

    float qk = q.x * k.x + q.y * k.y + q.z * k.z + q.w * k.w;
    float nm = q.x * ks.x + q.y * ks.y + q.z * ks.z + q.w * ks.w;
#pragma unroll
    for (int off = 1; off < 16; off <<= 1) {  // per-head reduce (16 lanes/head)
        qk += __shfl_xor(qk, off, 64);
        nm += __shfl_xor(nm, off, 64);
    }
    const float sc = qk / (nm + 1e-6f);
    float z[4] = {v.x * sc, v.y * sc, v.z * sc, v.w * sc};

    __shared__ float red[8];
    const int wv = tid >> 6, lane = tid & 63;

    float s1 = z[0] + z[1] + z[2] + z[3];
#pragma unroll
    for (int off = 1; off < 64; off <<= 1) s1 += __shfl_xor(s1, off, 64);
    if (lane == 0) red[wv] = s1;
    __syncthreads();
    const float mu = (red[0] + red[1] + red[2] + red[3]) * (1.0f / 1024.0f);

    float d[4] = {z[0] - mu, z[1] - mu, z[2] - mu, z[3] - mu};
    float s2 = d[0] * d[0] + d[1] * d[1] + d[2] * d[2] + d[3] * d[3];
#pragma unroll
    for (int off = 1; off < 64; off <<= 1) s2 += __shfl_xor(s2, off, 64);
    __syncthreads();
    if (lane == 0) red[4 + wv] = s2;
    __syncthreads();
    const float var = (red[4] + red[5] + red[6] + red[7]) * (1.0f / 1024.0f);
    const float rstd = rsqrtf(var + 1e-5f);

    const float4 gm = ((const float4*)gamma)[tid];
    const float4 bt = ((const float4*)beta)[tid];
    const float4 g = ((const float4*)(gd + (size_t)tl * HDIM))[tid];
    const float gv[4] = {g.x, g.y, g.z, g.w};
    const float gmv[4] = {gm.x, gm.y, gm.z, gm.w};
    const float btv[4] = {bt.x, bt.y, bt.z, bt.w};

    float o[4];
#pragma unroll
    for (int c = 0; c < 4; ++c) {
        const float zn = d[c] * rstd * gmv[c] + btv[c];
        const float sg = gv[c] / (1.0f + expf(-gv[c]));  // silu
        o[c] = zn * sg;
    }
    float4 u = {o[0], o[1], o[2], o[3]};
    ((float4*)(kz + (size_t)t * HDIM))[tid] = u;  // overwrite own 16B of k with z
}

// ---------------- launcher ----------------
extern "C" void kernel_launch(void* const* d_in, const int* in_sizes, int n_in,
                              void* d_out, int out_size, void* d_ws, size_t ws_size,
                              hipStream_t stream) {
    const float* hidden = (const float*)d_in[0];
    const float* Wq = (const float*)d_in[1];
    const float* Wk = (const float*)d_in[2];
    const float* Wv = (const float*)d_in[3];
    const float* Wg = (const float*)d_in[4];
    const float* Wo = (const float*)d_in[5];
    const float* gamma = (const float*)d_in[6];
    const float* beta = (const float*)d_in[7];

    // workspace (~109 MB)
    const size_t TH = (size_t)T_TOK * HDIM;
    const size_t CH = (size_t)CROWS * HDIM;
    float* kb = (float*)d_ws;        // 64 MB (k, later overwritten by z)
    float* qc = kb + TH;             // 8 MB
    float* vc = qc + CH;             // 8 MB
    float* gc = vc + CH;             // 8 MB
    ushort_t* WT2 = (ushort_t*)(gc + CH);       // 5 x 4 MB = 20 MB (k,q,v,g,o)
    float* partial = (float*)(WT2 + (size_t)5 * HDIM * 2048);  // 1 MB
    float* ksum = partial + (size_t)256 * HDIM;  // 8 KB

    ushort_t* Wk2 = WT2;
    ushort_t* Wq2 = WT2 + (size_t)1 * HDIM * 2048;
    ushort_t* Wv2 = WT2 + (size_t)2 * HDIM * 2048;
    ushort_t* Wg2 = WT2 + (size_t)3 * HDIM * 2048;
    ushort_t* Wo2 = WT2 + (size_t)4 * HDIM * 2048;

    split_w<<<dim3(32, 32, 5), 256, 0, stream>>>(Wk, Wq, Wv, Wg, Wo, WT2);

    // k = elu(h@Wk)+1
    gemm_split<0><<<dim3(128, 8), 256, 0, stream>>>(hidden, Wk2, nullptr, nullptr,
                                                    kb, nullptr, nullptr, HDIM);
    // ksum (deterministic)
    ksum_partial<<<dim3(256), 256, 0, stream>>>(kb, partial);
    ksum_reduce<<<dim3(4, 2), 256, 0, stream>>>(partial, ksum);

    // 8 chunks of 2048 tokens
    for (int c = 0; c < 8; ++c) {
        const float* Ac = hidden + (size_t)c * CH;
        gemm_split<1><<<dim3(CROWS / 128, 24), 256, 0, stream>>>(Ac, Wq2, Wv2, Wg2,
                                                                 qc, vc, gc, HDIM);
        token_f32<<<dim3(CROWS), 256, 0, stream>>>(qc, vc, gc, kb, ksum,
                                                   gamma, beta, c * CROWS);
    }

    // out = z @ Wo
    gemm_split<2><<<dim3(128, 8), 256, 0, stream>>>(kb, Wo2, nullptr, nullptr,
                                                    (float*)d_out, nullptr, nullptr, HDIM);
}

// Round 5
// 1012.444 us; speedup vs baseline: 2.2638x; 1.5541x over previous
//
#include <hip/hip_runtime.h>

// GatedLinearAttention, fp32 I/O, split-bf16 MFMA GEMMs (m97-style K-loop).
// B=2, S=8192, H=1024, NH=16, T=16384 tokens.
//
// fp32 x = hi + lo (bf16 each);  A@B ~= Ahi@Bhi + Alo@Bhi + Ahi@Blo.
// Stored as A' rows [hi(1024)|lo(1024)], B' rows [hi(1024)|lo(1024)].
// The 3 terms = ONE K=3072 GEMM with phased base offsets:
//   k0 in [0,1024):    A off k0        (hi), B off k0        (hi)
//   k0 in [1024,2048): A off k0        (lo), B off k0-1024   (hi)
//   k0 in [2048,3072): A off k0-2048   (hi), B off k0-1024   (lo)
// Inner loop: global_load_lds dwordx4 staging (no VALU), ds_read_b128 + MFMA.
//
// Workspace tiers (selected by ws_size at launch):
//   T1 >=342MB: Hs + full q,v,g  -> single fused kqvg GEMM (grid 128x32)
//   T2 >=198MB: Hs + chunk 4096  -> k GEMM + 4x qvg GEMM
//   T3 >=174MB: Hs + chunk 2048  -> k GEMM + 8x qvg GEMM
//   T4 else   : round-4 on-the-fly-split GEMMs for projections (proven 109MB)
// All tiers: token kernel writes z as bf16 hi|lo over k's rows (Zs), and the
// out GEMM is the new m97-style kernel reading Zs.

typedef unsigned short ushort_t;
typedef unsigned int uint_t;

using short8  = __attribute__((ext_vector_type(8))) short;
using floatx4 = __attribute__((ext_vector_type(4))) float;

#define HDIM  1024
#define T_TOK 16384
#define KSPLIT 3072

__device__ __forceinline__ ushort_t f2bf(float f) {
    uint_t u = __builtin_bit_cast(uint_t, f);
    u = (u + 0x7fff + ((u >> 16) & 1)) >> 16;  // RNE
    return (ushort_t)u;
}
__device__ __forceinline__ float bf2f(ushort_t h) {
    uint_t u = ((uint_t)h) << 16;
    return __builtin_bit_cast(float, u);
}
__device__ __forceinline__ void split2(float f, ushort_t& hi, ushort_t& lo) {
    hi = f2bf(f);
    lo = f2bf(f - bf2f(hi));
}
__device__ __forceinline__ void gload_lds16(const ushort_t* g, ushort_t* l) {
    __builtin_amdgcn_global_load_lds(
        (const __attribute__((address_space(1))) void*)g,
        (__attribute__((address_space(3))) void*)l, 16, 0, 0);
}

// ---------------- weight split+transpose: W[k][n] fp32 -> WT2[n][2048] bf16 hi|lo ----------------
__global__ void split_w(const float* __restrict__ W0, const float* __restrict__ W1,
                        const float* __restrict__ W2, const float* __restrict__ W3,
                        const float* __restrict__ W4, ushort_t* __restrict__ WT2) {
    __shared__ float tile[32][33];
    const int z = blockIdx.z;
    const float* W = (z == 0) ? W0 : (z == 1) ? W1 : (z == 2) ? W2 : (z == 3) ? W3 : W4;
    ushort_t* dst = WT2 + (size_t)z * HDIM * 2048;
    const int n0 = blockIdx.x * 32, k0 = blockIdx.y * 32;
    const int tx = threadIdx.x & 31, ty0 = threadIdx.x >> 5;
#pragma unroll
    for (int s = 0; s < 4; ++s) {
        int ty = ty0 + 8 * s;
        tile[ty][tx] = W[(size_t)(k0 + ty) * HDIM + n0 + tx];
    }
    __syncthreads();
#pragma unroll
    for (int s = 0; s < 4; ++s) {
        int ty = ty0 + 8 * s;
        float v = tile[tx][ty];
        ushort_t hi, lo;
        split2(v, hi, lo);
        dst[(size_t)(n0 + ty) * 2048 + k0 + tx] = hi;
        dst[(size_t)(n0 + ty) * 2048 + 1024 + k0 + tx] = lo;
    }
}

// ---------------- hidden split: h[t][1024] fp32 -> Hs[t][2048] bf16 hi|lo ----------------
__global__ __launch_bounds__(256)
void split_hidden(const float* __restrict__ h, ushort_t* __restrict__ Hs) {
    const int t = blockIdx.x;
    const int c = threadIdx.x;
    const float4 x = ((const float4*)(h + (size_t)t * HDIM))[c];
    ushort_t hi[4], lo[4];
    split2(x.x, hi[0], lo[0]); split2(x.y, hi[1], lo[1]);
    split2(x.z, hi[2], lo[2]); split2(x.w, hi[3], lo[3]);
    ushort_t* row = Hs + (size_t)t * 2048;
    uint2 hp, lp;
    hp.x = (uint_t)hi[0] | ((uint_t)hi[1] << 16);
    hp.y = (uint_t)hi[2] | ((uint_t)hi[3] << 16);
    lp.x = (uint_t)lo[0] | ((uint_t)lo[1] << 16);
    lp.y = (uint_t)lo[2] | ((uint_t)lo[3] << 16);
    *(uint2*)(row + c * 4) = hp;
    *(uint2*)(row + 1024 + c * 4) = lp;
}

// ---------------- m97-style split GEMM: 128x128 tile, BK=64, K=3072 phased ----------------
// A [M rows][2048] bf16 hi|lo. Bbase rows [n][2048] bf16 hi|lo (weights contiguous k,q,v,g).
// Grid (M/128, nW*8): wsel=by>>3 selects dst; col-in-weight = (by&7)*128.
// actmask bit wsel => apply elu(x)+1.
__global__ __launch_bounds__(256)
void gemm_m97(const ushort_t* __restrict__ A, const ushort_t* __restrict__ Bbase,
              float* __restrict__ d0, float* __restrict__ d1,
              float* __restrict__ d2, float* __restrict__ d3, int actmask) {
    __shared__ ushort_t As[128 * 64];
    __shared__ ushort_t Bs[128 * 64];
    const int tid = threadIdx.x;
    const int bx = blockIdx.x, by = blockIdx.y;
    const int w = tid >> 6, lane = tid & 63;
    const int wm = w & 1, wn = w >> 1;
    const int lrow = lane & 15, lq = lane >> 4;

    const int wsel = by >> 3;
    float* D = (wsel == 0) ? d0 : (wsel == 1) ? d1 : (wsel == 2) ? d2 : d3;
    const bool act = (actmask >> wsel) & 1;

    // staging: wave w covers rows w*32 + n*8 + lane/8, 16B chunk (lane%8)*8 elems
    const int srow = lane >> 3;
    const int scol = (lane & 7) * 8;
    const ushort_t* Ag = A + (size_t)(bx * 128 + w * 32 + srow) * 2048 + scol;
    const ushort_t* Bg = Bbase + (size_t)(by * 128 + w * 32 + srow) * 2048 + scol;

    floatx4 acc[4][4] = {};

    for (int k0 = 0; k0 < KSPLIT; k0 += 64) {
        const int ka = k0 - ((k0 >= 2048) ? 2048 : 0);   // A: hi | lo | hi
        const int kb = k0 - ((k0 >= 1024) ? 1024 : 0);   // B: hi | hi | lo
        __syncthreads();  // previous iter's ds_reads done before overwrite
#pragma unroll
        for (int n = 0; n < 4; ++n) {
            gload_lds16(Ag + (size_t)(n * 8) * 2048 + ka, &As[(w * 32 + n * 8) * 64]);
            gload_lds16(Bg + (size_t)(n * 8) * 2048 + kb, &Bs[(w * 32 + n * 8) * 64]);
        }
        __syncthreads();  // drains vmcnt: LDS tiles visible
#pragma unroll
        for (int kk = 0; kk < 64; kk += 32) {
            short8 af[4], bf[4];
#pragma unroll
            for (int i = 0; i < 4; ++i)
                af[i] = *(const short8*)&As[(wm * 64 + i * 16 + lrow) * 64 + kk + lq * 8];
#pragma unroll
            for (int j = 0; j < 4; ++j)
                bf[j] = *(const short8*)&Bs[(wn * 64 + j * 16 + lrow) * 64 + kk + lq * 8];
#pragma unroll
            for (int i = 0; i < 4; ++i)
#pragma unroll
                for (int j = 0; j < 4; ++j)
                    acc[i][j] = __builtin_amdgcn_mfma_f32_16x16x32_bf16(af[i], bf[j], acc[i][j], 0, 0, 0);
        }
    }

    // C[row][col] (m89/m91 layout, verified in-session by round-4 pass)
    const int rowbase = bx * 128 + wm * 64 + lq * 4;
    const int colbase = (by & 7) * 128 + wn * 64 + lrow;
#pragma unroll
    for (int i = 0; i < 4; ++i)
#pragma unroll
        for (int j = 0; j < 4; ++j) {
            const int col = colbase + j * 16;
#pragma unroll
            for (int r = 0; r < 4; ++r) {
                const int row = rowbase + i * 16 + r;
                float val = acc[i][j][r];
                if (act) val = (val > 0.0f) ? (val + 1.0f) : (expm1f(val) + 1.0f);
                D[(size_t)row * HDIM + col] = val;
            }
        }
}

// ---------------- round-4 on-the-fly-split GEMM (T4 fallback projections) ----------------
template <int VAR>  // 0: D0=elu(A@B0)+1 ; 1: wsel=by>>3 -> q(elu)/v/g
__global__ __launch_bounds__(256, 2)
void gemm_split(const float* __restrict__ A,
                const ushort_t* __restrict__ B0, const ushort_t* __restrict__ B1,
                const ushort_t* __restrict__ B2,
                float* __restrict__ D0, float* __restrict__ D1, float* __restrict__ D2,
                int K) {
    __shared__ ushort_t Ah[128 * 72];
    __shared__ ushort_t Al[128 * 72];
    __shared__ ushort_t Bh[128 * 72];
    __shared__ ushort_t Bl[128 * 72];

    const int tid = threadIdx.x;
    const int bx = blockIdx.x, by = blockIdx.y;

    const ushort_t* Bt;
    float* D;
    int n0;
    bool act;
    if (VAR == 1) {
        const int wsel = by >> 3;
        Bt = (wsel == 0) ? B0 : (wsel == 1) ? B1 : B2;
        D = (wsel == 0) ? D0 : (wsel == 1) ? D1 : D2;
        n0 = (by & 7) * 128;
        act = (wsel == 0);
    } else {
        Bt = B0; D = D0; n0 = by * 128; act = true;
    }

    const int w = tid >> 6, lane = tid & 63;
    const int wm = w & 1, wn = w >> 1;
    const int lrow = lane & 15, lq = lane >> 4;

    const int srow = tid >> 1;
    const int shalf = (tid & 1) * 32;
    const float* Arow = A + (size_t)(bx * 128 + srow) * K;
    const ushort_t* Brow = Bt + (size_t)(n0 + srow) * 2048;

    floatx4 acc[4][4] = {};

    for (int k0 = 0; k0 < K; k0 += 64) {
        float4 afr[8];
        uint4 bhr[4], blr[4];
#pragma unroll
        for (int g = 0; g < 4; ++g) {
            afr[2 * g]     = *(const float4*)(Arow + k0 + shalf + g * 8);
            afr[2 * g + 1] = *(const float4*)(Arow + k0 + shalf + g * 8 + 4);
            bhr[g] = *(const uint4*)(Brow + k0 + shalf + g * 8);
            blr[g] = *(const uint4*)(Brow + 1024 + k0 + shalf + g * 8);
        }
        __syncthreads();
#pragma unroll
        for (int g = 0; g < 4; ++g) {
            ushort_t h[8], l[8];
            const float4 f0 = afr[2 * g], f1 = afr[2 * g + 1];
            split2(f0.x, h[0], l[0]); split2(f0.y, h[1], l[1]);
            split2(f0.z, h[2], l[2]); split2(f0.w, h[3], l[3]);
            split2(f1.x, h[4], l[4]); split2(f1.y, h[5], l[5]);
            split2(f1.z, h[6], l[6]); split2(f1.w, h[7], l[7]);
            uint4 hp, lp;
            hp.x = (uint_t)h[0] | ((uint_t)h[1] << 16);
            hp.y = (uint_t)h[2] | ((uint_t)h[3] << 16);
            hp.z = (uint_t)h[4] | ((uint_t)h[5] << 16);
            hp.w = (uint_t)h[6] | ((uint_t)h[7] << 16);
            lp.x = (uint_t)l[0] | ((uint_t)l[1] << 16);
            lp.y = (uint_t)l[2] | ((uint_t)l[3] << 16);
            lp.z = (uint_t)l[4] | ((uint_t)l[5] << 16);
            lp.w = (uint_t)l[6] | ((uint_t)l[7] << 16);
            *(uint4*)&Ah[srow * 72 + shalf + g * 8] = hp;
            *(uint4*)&Al[srow * 72 + shalf + g * 8] = lp;
            *(uint4*)&Bh[srow * 72 + shalf + g * 8] = bhr[g];
            *(uint4*)&Bl[srow * 72 + shalf + g * 8] = blr[g];
        }
        __syncthreads();
#pragma unroll
        for (int kk = 0; kk < 64; kk += 32) {
            short8 ah[4], bh[4], xl[4];
#pragma unroll
            for (int i = 0; i < 4; ++i)
                ah[i] = *(const short8*)&Ah[(wm * 64 + i * 16 + lrow) * 72 + kk + lq * 8];
#pragma unroll
            for (int j = 0; j < 4; ++j)
                bh[j] = *(const short8*)&Bh[(wn * 64 + j * 16 + lrow) * 72 + kk + lq * 8];
#pragma unroll
            for (int i = 0; i < 4; ++i)
#pragma unroll
                for (int j = 0; j < 4; ++j)
                    acc[i][j] = __builtin_amdgcn_mfma_f32_16x16x32_bf16(ah[i], bh[j], acc[i][j], 0, 0, 0);
#pragma unroll
            for (int i = 0; i < 4; ++i)
                xl[i] = *(const short8*)&Al[(wm * 64 + i * 16 + lrow) * 72 + kk + lq * 8];
#pragma unroll
            for (int i = 0; i < 4; ++i)
#pragma unroll
                for (int j = 0; j < 4; ++j)
                    acc[i][j] = __builtin_amdgcn_mfma_f32_16x16x32_bf16(xl[i], bh[j], acc[i][j], 0, 0, 0);
#pragma unroll
            for (int j = 0; j < 4; ++j)
                xl[j] = *(const short8*)&Bl[(wn * 64 + j * 16 + lrow) * 72 + kk + lq * 8];
#pragma unroll
            for (int i = 0; i < 4; ++i)
#pragma unroll
                for (int j = 0; j < 4; ++j)
                    acc[i][j] = __builtin_amdgcn_mfma_f32_16x16x32_bf16(ah[i], xl[j], acc[i][j], 0, 0, 0);
        }
    }

    const int rowbase = bx * 128 + wm * 64 + lq * 4;
    const int colbase = n0 + wn * 64 + lrow;
#pragma unroll
    for (int i = 0; i < 4; ++i)
#pragma unroll
        for (int j = 0; j < 4; ++j) {
            const int col = colbase + j * 16;
#pragma unroll
            for (int r = 0; r < 4; ++r) {
                const int row = rowbase + i * 16 + r;
                float val = acc[i][j][r];
                if (act) val = (val > 0.0f) ? (val + 1.0f) : (expm1f(val) + 1.0f);
                D[(size_t)row * HDIM + col] = val;
            }
        }
}

// ---------------- ksum: deterministic two-stage ----------------
__global__ void ksum_partial(const float* __restrict__ kf, float* __restrict__ partial) {
    const int rg = blockIdx.x;
    const int tid = threadIdx.x;
    const float4* p = (const float4*)(kf + (size_t)rg * 64 * HDIM) + tid;
    float4 s = {0.f, 0.f, 0.f, 0.f};
    for (int r = 0; r < 64; ++r) {
        float4 x = p[(size_t)r * (HDIM / 4)];
        s.x += x.x; s.y += x.y; s.z += x.z; s.w += x.w;
    }
    ((float4*)(partial + (size_t)rg * HDIM))[tid] = s;
}
__global__ void ksum_reduce(const float* __restrict__ partial, float* __restrict__ ksum) {
    const int b = blockIdx.y;
    const int c = blockIdx.x * 256 + threadIdx.x;
    float s = 0.f;
    const float* p = partial + (size_t)b * 128 * HDIM + c;
    for (int rg = 0; rg < 128; ++rg) s += p[(size_t)rg * HDIM];
    ksum[b * HDIM + c] = s;
}

// ---------------- per-token: z, LayerNorm, SiLU gate -> Zs bf16 hi|lo over k rows ----------------
__global__ __launch_bounds__(256)
void token_f32(const float* __restrict__ qd, const float* __restrict__ vd,
               const float* __restrict__ gd, float* kz,
               const float* __restrict__ ksum,
               const float* __restrict__ gamma, const float* __restrict__ beta,
               int chunk_base) {
    const int tl = blockIdx.x;
    const int t = chunk_base + tl;
    const int b = t >> 13;
    const int tid = threadIdx.x;

    const float4 q = ((const float4*)(qd + (size_t)tl * HDIM))[tid];
    const float4 k = ((const float4*)(kz + (size_t)t * HDIM))[tid];
    const float4 v = ((const float4*)(vd + (size_t)tl * HDIM))[tid];
    const float4 ks = ((const float4*)(ksum + (size_t)b * HDIM))[tid];

    float qk = q.x * k.x + q.y * k.y + q.z * k.z + q.w * k.w;
    float nm = q.x * ks.x + q.y * ks.y + q.z * ks.z + q.w * ks.w;
#pragma unroll
    for (int off = 1; off < 16; off <<= 1) {
        qk += __shfl_xor(qk, off, 64);
        nm += __shfl_xor(nm, off, 64);
    }
    const float sc = qk / (nm + 1e-6f);
    float z[4] = {v.x * sc, v.y * sc, v.z * sc, v.w * sc};

    __shared__ float red[8];
    const int wv = tid >> 6, lane = tid & 63;

    float s1 = z[0] + z[1] + z[2] + z[3];
#pragma unroll
    for (int off = 1; off < 64; off <<= 1) s1 += __shfl_xor(s1, off, 64);
    if (lane == 0) red[wv] = s1;
    __syncthreads();   // also orders: all k-reads precede any Zs store below
    const float mu = (red[0] + red[1] + red[2] + red[3]) * (1.0f / 1024.0f);

    float d[4] = {z[0] - mu, z[1] - mu, z[2] - mu, z[3] - mu};
    float s2 = d[0] * d[0] + d[1] * d[1] + d[2] * d[2] + d[3] * d[3];
#pragma unroll
    for (int off = 1; off < 64; off <<= 1) s2 += __shfl_xor(s2, off, 64);
    __syncthreads();
    if (lane == 0) red[4 + wv] = s2;
    __syncthreads();
    const float var = (red[4] + red[5] + red[6] + red[7]) * (1.0f / 1024.0f);
    const float rstd = rsqrtf(var + 1e-5f);

    const float4 gm = ((const float4*)gamma)[tid];
    const float4 bt = ((const float4*)beta)[tid];
    const float4 g = ((const float4*)(gd + (size_t)tl * HDIM))[tid];
    const float gv[4] = {g.x, g.y, g.z, g.w};
    const float gmv[4] = {gm.x, gm.y, gm.z, gm.w};
    const float btv[4] = {bt.x, bt.y, bt.z, bt.w};

    ushort_t hi[4], lo[4];
#pragma unroll
    for (int c = 0; c < 4; ++c) {
        const float zn = d[c] * rstd * gmv[c] + btv[c];
        const float sg = gv[c] / (1.0f + expf(-gv[c]));
        split2(zn * sg, hi[c], lo[c]);
    }
    // Zs layout [t][2048]: hi block then lo block (matches gemm_m97 A phasing)
    ushort_t* zrow = (ushort_t*)(kz + (size_t)t * HDIM);
    uint2 hp, lp;
    hp.x = (uint_t)hi[0] | ((uint_t)hi[1] << 16);
    hp.y = (uint_t)hi[2] | ((uint_t)hi[3] << 16);
    lp.x = (uint_t)lo[0] | ((uint_t)lo[1] << 16);
    lp.y = (uint_t)lo[2] | ((uint_t)lo[3] << 16);
    *(uint2*)(zrow + tid * 4) = hp;
    *(uint2*)(zrow + 1024 + tid * 4) = lp;
}

// ---------------- launcher ----------------
extern "C" void kernel_launch(void* const* d_in, const int* in_sizes, int n_in,
                              void* d_out, int out_size, void* d_ws, size_t ws_size,
                              hipStream_t stream) {
    const float* hidden = (const float*)d_in[0];
    const float* Wq = (const float*)d_in[1];
    const float* Wk = (const float*)d_in[2];
    const float* Wv = (const float*)d_in[3];
    const float* Wg = (const float*)d_in[4];
    const float* Wo = (const float*)d_in[5];
    const float* gamma = (const float*)d_in[6];
    const float* beta = (const float*)d_in[7];

    char* w = (char*)d_ws;
    float* kb = (float*)w;            w += (size_t)67108864;   // k fp32, later Zs bf16 hi|lo
    ushort_t* WT2 = (ushort_t*)w;     w += (size_t)20971520;   // 5 weights split [n][2048]
    float* partial = (float*)w;       w += (size_t)1048576;
    float* ksum = (float*)w;          w += (size_t)8192;
    const size_t base = (size_t)(w - (char*)d_ws);             // 89,137,152 B

    ushort_t* Wk2 = WT2;
    ushort_t* Wq2 = WT2 + (size_t)1 * HDIM * 2048;
    ushort_t* Wv2 = WT2 + (size_t)2 * HDIM * 2048;
    ushort_t* Wg2 = WT2 + (size_t)3 * HDIM * 2048;
    ushort_t* Wo2 = WT2 + (size_t)4 * HDIM * 2048;

    // tier select
    ushort_t* Hs = nullptr;
    float *qc = nullptr, *vc = nullptr, *gc = nullptr;
    int C = 0, nchunk = 0, tier;
    if (ws_size >= base + 67108864ull + 201326592ull) {        // T1: 341 MB
        tier = 1; C = T_TOK; nchunk = 1;
    } else if (ws_size >= base + 67108864ull + 50331648ull) {  // T2: 197 MB
        tier = 2; C = 4096; nchunk = 4;
    } else if (ws_size >= base + 67108864ull + 25165824ull) {  // T3: 173 MB
        tier = 3; C = 2048; nchunk = 8;
    } else {                                                   // T4: 109 MB (proven)
        tier = 4; C = 2048; nchunk = 8;
    }
    if (tier != 4) { Hs = (ushort_t*)w; w += (size_t)67108864; }
    qc = (float*)w; w += (size_t)C * HDIM * 4;
    vc = (float*)w; w += (size_t)C * HDIM * 4;
    gc = (float*)w; w += (size_t)C * HDIM * 4;

    split_w<<<dim3(32, 32, 5), 256, 0, stream>>>(Wk, Wq, Wv, Wg, Wo, WT2);
    if (Hs) split_hidden<<<dim3(T_TOK), 256, 0, stream>>>(hidden, Hs);

    if (tier == 1) {
        // fused k|q|v|g projection, N=4096
        gemm_m97<<<dim3(128, 32), 256, 0, stream>>>(Hs, Wk2, kb, qc, vc, gc, 0b0011);
        ksum_partial<<<dim3(256), 256, 0, stream>>>(kb, partial);
        ksum_reduce<<<dim3(4, 2), 256, 0, stream>>>(partial, ksum);
        token_f32<<<dim3(T_TOK), 256, 0, stream>>>(qc, vc, gc, kb, ksum, gamma, beta, 0);
    } else if (tier != 4) {
        gemm_m97<<<dim3(128, 8), 256, 0, stream>>>(Hs, Wk2, kb, kb, kb, kb, 1);
        ksum_partial<<<dim3(256), 256, 0, stream>>>(kb, partial);
        ksum_reduce<<<dim3(4, 2), 256, 0, stream>>>(partial, ksum);
        for (int c = 0; c < nchunk; ++c) {
            gemm_m97<<<dim3(C / 128, 24), 256, 0, stream>>>(Hs + (size_t)c * C * 2048, Wq2,
                                                            qc, vc, gc, gc, 0b001);
            token_f32<<<dim3(C), 256, 0, stream>>>(qc, vc, gc, kb, ksum, gamma, beta, c * C);
        }
    } else {
        gemm_split<0><<<dim3(128, 8), 256, 0, stream>>>(hidden, Wk2, nullptr, nullptr,
                                                        kb, nullptr, nullptr, HDIM);
        ksum_partial<<<dim3(256), 256, 0, stream>>>(kb, partial);
        ksum_reduce<<<dim3(4, 2), 256, 0, stream>>>(partial, ksum);
        for (int c = 0; c < nchunk; ++c) {
            const float* Ac = hidden + (size_t)c * C * HDIM;
            gemm_split<1><<<dim3(C / 128, 24), 256, 0, stream>>>(Ac, Wq2, Wv2, Wg2,
                                                                 qc, vc, gc, HDIM);
            token_f32<<<dim3(C), 256, 0, stream>>>(qc, vc, gc, kb, ksum, gamma, beta, c * C);
        }
    }

    // out = z @ Wo  (A = Zs aliased over kb)
    gemm_m97<<<dim3(128, 8), 256, 0, stream>>>((const ushort_t*)kb, Wo2,
                                               (float*)d_out, (float*)d_out,
                                               (float*)d_out, (float*)d_out, 0);
}

// Round 6
// 853.267 us; speedup vs baseline: 2.6861x; 1.1866x over previous
//
#include <hip/hip_runtime.h>

// GatedLinearAttention, fp32 I/O, split-bf16 MFMA GEMMs, XOR-swizzled LDS.
// B=2, S=8192, H=1024, NH=16, T=16384 tokens.
//
// fp32 x = hi + lo (bf16);  A@B ~= Ahi@Bhi + Alo@Bhi + Ahi@Blo  == one K=3072
// GEMM with phased base offsets (A: hi|lo|hi, B: hi|hi|lo).
//
// LDS bank-conflict fix: global_load_lds forces LDS addr = base + lane*16B, so
// instead of padding we swizzle WHICH global 16B chunk each lane fetches:
//   LDS As[row][chunk c] = global chunk (c ^ (row&7)).
// Read side XORs back -> quad-group (16 lanes, rows r..r+15) spreads over all
// 32 banks (2 lanes/bank = free) instead of 16-way conflicting on 4 banks.
//
// Pipeline (ws ~150 MB, all GEMMs full grid 128x8 = 1024 blocks):
//   split_w, split_hidden -> Hs
//   K:  kb = elu(h@Wk)+1 fp32            [EPI 0]
//   ksum (two-stage deterministic)
//   Q:  epilogue computes sc[t][head] = (q.k)/(q.ksum+eps); q never stored [EPI 1]
//   V:  v = h@Wv fp32, written OVER kb (k dead after Q)                    [EPI 2]
//   token_lite: z = v*sc, LayerNorm -> zn bf16 hi|lo in place over v rows
//   G:  epilogue gates zn *= silu(g) in place (per-lane RMW)              [EPI 3]
//   O:  out = Zs @ Wo fp32                                                 [EPI 2]
// Fallback (ws < 150 MB): round-4 proven on-the-fly-split path (~110 MB).

typedef unsigned short ushort_t;
typedef unsigned int uint_t;

using short8  = __attribute__((ext_vector_type(8))) short;
using floatx4 = __attribute__((ext_vector_type(4))) float;

#define HDIM  1024
#define T_TOK 16384
#define KSPLIT 3072

__device__ __forceinline__ ushort_t f2bf(float f) {
    uint_t u = __builtin_bit_cast(uint_t, f);
    u = (u + 0x7fff + ((u >> 16) & 1)) >> 16;  // RNE
    return (ushort_t)u;
}
__device__ __forceinline__ float bf2f(ushort_t h) {
    uint_t u = ((uint_t)h) << 16;
    return __builtin_bit_cast(float, u);
}
__device__ __forceinline__ void split2(float f, ushort_t& hi, ushort_t& lo) {
    hi = f2bf(f);
    lo = f2bf(f - bf2f(hi));
}
__device__ __forceinline__ void gload_lds16(const ushort_t* g, ushort_t* l) {
    __builtin_amdgcn_global_load_lds(
        (const __attribute__((address_space(1))) void*)g,
        (__attribute__((address_space(3))) void*)l, 16, 0, 0);
}

// ---------------- weight split+transpose: W[k][n] fp32 -> WT2[n][2048] bf16 hi|lo ----------------
__global__ void split_w(const float* __restrict__ W0, const float* __restrict__ W1,
                        const float* __restrict__ W2, const float* __restrict__ W3,
                        const float* __restrict__ W4, ushort_t* __restrict__ WT2) {
    __shared__ float tile[32][33];
    const int z = blockIdx.z;
    const float* W = (z == 0) ? W0 : (z == 1) ? W1 : (z == 2) ? W2 : (z == 3) ? W3 : W4;
    ushort_t* dst = WT2 + (size_t)z * HDIM * 2048;
    const int n0 = blockIdx.x * 32, k0 = blockIdx.y * 32;
    const int tx = threadIdx.x & 31, ty0 = threadIdx.x >> 5;
#pragma unroll
    for (int s = 0; s < 4; ++s) {
        int ty = ty0 + 8 * s;
        tile[ty][tx] = W[(size_t)(k0 + ty) * HDIM + n0 + tx];
    }
    __syncthreads();
#pragma unroll
    for (int s = 0; s < 4; ++s) {
        int ty = ty0 + 8 * s;
        float v = tile[tx][ty];
        ushort_t hi, lo;
        split2(v, hi, lo);
        dst[(size_t)(n0 + ty) * 2048 + k0 + tx] = hi;
        dst[(size_t)(n0 + ty) * 2048 + 1024 + k0 + tx] = lo;
    }
}

// ---------------- hidden split: h[t][1024] fp32 -> Hs[t][2048] bf16 hi|lo ----------------
__global__ __launch_bounds__(256)
void split_hidden(const float* __restrict__ h, ushort_t* __restrict__ Hs) {
    const int t = blockIdx.x;
    const int c = threadIdx.x;
    const float4 x = ((const float4*)(h + (size_t)t * HDIM))[c];
    ushort_t hi[4], lo[4];
    split2(x.x, hi[0], lo[0]); split2(x.y, hi[1], lo[1]);
    split2(x.z, hi[2], lo[2]); split2(x.w, hi[3], lo[3]);
    ushort_t* row = Hs + (size_t)t * 2048;
    uint2 hp, lp;
    hp.x = (uint_t)hi[0] | ((uint_t)hi[1] << 16);
    hp.y = (uint_t)hi[2] | ((uint_t)hi[3] << 16);
    lp.x = (uint_t)lo[0] | ((uint_t)lo[1] << 16);
    lp.y = (uint_t)lo[2] | ((uint_t)lo[3] << 16);
    *(uint2*)(row + c * 4) = hp;
    *(uint2*)(row + 1024 + c * 4) = lp;
}

// ---------------- swizzled m97-style split GEMM, 128x128 tile, BK=64, K=3072 ----------------
// EPI 0: D = elu(A@B)+1 fp32     EPI 1: sc-reduction (q; uses kf,ksum,scbuf)
// EPI 2: D = A@B fp32            EPI 3: gate RMW on zbuf (g)
template <int EPI>
__global__ __launch_bounds__(256)
void gemm_swz(const ushort_t* __restrict__ A, const ushort_t* __restrict__ Bw,
              float* __restrict__ D, const float* __restrict__ kf,
              const float* __restrict__ ksum, float* __restrict__ scbuf,
              ushort_t* __restrict__ zbuf) {
    __shared__ ushort_t As[128 * 64];
    __shared__ ushort_t Bs[128 * 64];
    const int tid = threadIdx.x;
    const int bx = blockIdx.x, by = blockIdx.y;
    const int w = tid >> 6, lane = tid & 63;
    const int wm = w & 1, wn = w >> 1;
    const int lrow = lane & 15, lq = lane >> 4;

    // staging: lane covers row w*32+n*8+(lane>>3), swizzled chunk ((lane&7)^(row&7))
    const int srow = lane >> 3;                       // 0..7, == row&7
    const int scol = ((lane & 7) ^ srow) * 8;         // swizzled 16B chunk
    const ushort_t* Ag = A + (size_t)(bx * 128 + w * 32 + srow) * 2048 + scol;
    const ushort_t* Bg = Bw + (size_t)(by * 128 + w * 32 + srow) * 2048 + scol;

    floatx4 acc[4][4] = {};

    for (int k0 = 0; k0 < KSPLIT; k0 += 64) {
        const int ka = k0 - ((k0 >= 2048) ? 2048 : 0);   // A: hi | lo | hi
        const int kb = k0 - ((k0 >= 1024) ? 1024 : 0);   // B: hi | hi | lo
        __syncthreads();
#pragma unroll
        for (int n = 0; n < 4; ++n) {
            gload_lds16(Ag + (size_t)(n * 8) * 2048 + ka, &As[(w * 32 + n * 8) * 64]);
            gload_lds16(Bg + (size_t)(n * 8) * 2048 + kb, &Bs[(w * 32 + n * 8) * 64]);
        }
        __syncthreads();
#pragma unroll
        for (int kk = 0; kk < 64; kk += 32) {
            short8 af[4], bf[4];
#pragma unroll
            for (int i = 0; i < 4; ++i) {
                const int c = (((kk >> 3) + lq) ^ (lrow & 7)) * 8;  // unswizzle
                af[i] = *(const short8*)&As[(wm * 64 + i * 16 + lrow) * 64 + c];
            }
#pragma unroll
            for (int j = 0; j < 4; ++j) {
                const int c = (((kk >> 3) + lq) ^ (lrow & 7)) * 8;
                bf[j] = *(const short8*)&Bs[(wn * 64 + j * 16 + lrow) * 64 + c];
            }
#pragma unroll
            for (int i = 0; i < 4; ++i)
#pragma unroll
                for (int j = 0; j < 4; ++j)
                    acc[i][j] = __builtin_amdgcn_mfma_f32_16x16x32_bf16(af[i], bf[j], acc[i][j], 0, 0, 0);
        }
    }

    const int rowbase = bx * 128 + wm * 64 + lq * 4;
    const int colbase = by * 128 + wn * 64 + lrow;

    if (EPI == 0 || EPI == 2) {
#pragma unroll
        for (int i = 0; i < 4; ++i)
#pragma unroll
            for (int j = 0; j < 4; ++j) {
                const int col = colbase + j * 16;
#pragma unroll
                for (int r = 0; r < 4; ++r) {
                    const int row = rowbase + i * 16 + r;
                    float val = acc[i][j][r];
                    if (EPI == 0) val = (val > 0.0f) ? (val + 1.0f) : (expm1f(val) + 1.0f);
                    D[(size_t)row * HDIM + col] = val;
                }
            }
    } else if (EPI == 1) {
        // q epilogue: head h = by*2 + wn spans cols [h*64, h*64+64) = this wave's j x lrow
        const int b = (bx * 128) >> 13;  // uniform per block
        float ksv[4];
#pragma unroll
        for (int j = 0; j < 4; ++j) ksv[j] = ksum[b * HDIM + colbase + j * 16];
        const int h = by * 2 + wn;
#pragma unroll
        for (int i = 0; i < 4; ++i)
#pragma unroll
            for (int r = 0; r < 4; ++r) {
                const int row = rowbase + i * 16 + r;
                float qk = 0.f, nm = 0.f;
#pragma unroll
                for (int j = 0; j < 4; ++j) {
                    float qv = acc[i][j][r];
                    qv = (qv > 0.0f) ? (qv + 1.0f) : (expm1f(qv) + 1.0f);
                    const float kv = kf[(size_t)row * HDIM + colbase + j * 16];
                    qk += qv * kv;
                    nm += qv * ksv[j];
                }
#pragma unroll
                for (int off = 1; off < 16; off <<= 1) {
                    qk += __shfl_xor(qk, off, 64);
                    nm += __shfl_xor(nm, off, 64);
                }
                if (lrow == 0) scbuf[row * 16 + h] = qk / (nm + 1e-6f);
            }
    } else {  // EPI == 3: gate zn *= silu(g), in-place RMW (one lane owns each (row,col))
#pragma unroll
        for (int i = 0; i < 4; ++i)
#pragma unroll
            for (int j = 0; j < 4; ++j) {
                const int col = colbase + j * 16;
#pragma unroll
                for (int r = 0; r < 4; ++r) {
                    const int row = rowbase + i * 16 + r;
                    ushort_t* zr = zbuf + (size_t)row * 2048;
                    const float zn = bf2f(zr[col]) + bf2f(zr[1024 + col]);
                    const float g = acc[i][j][r];
                    const float sg = g / (1.0f + expf(-g));
                    ushort_t hi, lo;
                    split2(zn * sg, hi, lo);
                    zr[col] = hi;
                    zr[1024 + col] = lo;
                }
            }
    }
}

// ---------------- ksum: deterministic two-stage ----------------
__global__ void ksum_partial(const float* __restrict__ kf, float* __restrict__ partial) {
    const int rg = blockIdx.x;
    const int tid = threadIdx.x;
    const float4* p = (const float4*)(kf + (size_t)rg * 64 * HDIM) + tid;
    float4 s = {0.f, 0.f, 0.f, 0.f};
    for (int r = 0; r < 64; ++r) {
        float4 x = p[(size_t)r * (HDIM / 4)];
        s.x += x.x; s.y += x.y; s.z += x.z; s.w += x.w;
    }
    ((float4*)(partial + (size_t)rg * HDIM))[tid] = s;
}
__global__ void ksum_reduce(const float* __restrict__ partial, float* __restrict__ ksum) {
    const int b = blockIdx.y;
    const int c = blockIdx.x * 256 + threadIdx.x;
    float s = 0.f;
    const float* p = partial + (size_t)b * 128 * HDIM + c;
    for (int rg = 0; rg < 128; ++rg) s += p[(size_t)rg * HDIM];
    ksum[b * HDIM + c] = s;
}

// ---------------- token-lite: z = v*sc, LayerNorm -> zn bf16 hi|lo in place ----------------
__global__ __launch_bounds__(256)
void token_lite(float* vz, const float* __restrict__ scbuf) {
    const int t = blockIdx.x;
    const int tid = threadIdx.x;
    const float4 v = ((const float4*)(vz + (size_t)t * HDIM))[tid];
    const float sc = scbuf[t * 16 + (tid >> 4)];
    float z[4] = {v.x * sc, v.y * sc, v.z * sc, v.w * sc};

    __shared__ float red[8];
    const int wv = tid >> 6, lane = tid & 63;

    float s1 = z[0] + z[1] + z[2] + z[3];
#pragma unroll
    for (int off = 1; off < 64; off <<= 1) s1 += __shfl_xor(s1, off, 64);
    if (lane == 0) red[wv] = s1;
    __syncthreads();
    const float mu = (red[0] + red[1] + red[2] + red[3]) * (1.0f / 1024.0f);

    float d[4] = {z[0] - mu, z[1] - mu, z[2] - mu, z[3] - mu};
    float s2 = d[0] * d[0] + d[1] * d[1] + d[2] * d[2] + d[3] * d[3];
#pragma unroll
    for (int off = 1; off < 64; off <<= 1) s2 += __shfl_xor(s2, off, 64);
    __syncthreads();
    if (lane == 0) red[4 + wv] = s2;
    __syncthreads();
    const float var = (red[4] + red[5] + red[6] + red[7]) * (1.0f / 1024.0f);
    const float rstd = rsqrtf(var + 1e-5f);

    // gamma=1, beta=0 in this problem is NOT assumed; LN affine folded in G-epilogue?
    // No: reference applies gamma/beta BEFORE gating. Handle here via constant mem? They
    // are inputs; apply now (loaded below).
    ushort_t* zrow = (ushort_t*)(vz + (size_t)t * HDIM);
    ushort_t hi[4], lo[4];
#pragma unroll
    for (int c = 0; c < 4; ++c) split2(d[c] * rstd, hi[c], lo[c]);
    uint2 hp, lp;
    hp.x = (uint_t)hi[0] | ((uint_t)hi[1] << 16);
    hp.y = (uint_t)hi[2] | ((uint_t)hi[3] << 16);
    lp.x = (uint_t)lo[0] | ((uint_t)lo[1] << 16);
    lp.y = (uint_t)lo[2] | ((uint_t)lo[3] << 16);
    *(uint2*)(zrow + tid * 4) = hp;
    *(uint2*)(zrow + 1024 + tid * 4) = lp;
}

// gamma/beta applied in G-epilogue would be wrong order vs silu? Reference:
// z = LN(z)*gamma+beta, then z *= silu(g). Both elementwise on the same col ->
// G-epilogue computes (zn*gamma[col]+beta[col])*silu(g). token_lite stores zn
// WITHOUT affine; gemm_gate applies affine+gate together.
template <int DUMMY>
__global__ __launch_bounds__(256)
void gemm_gate(const ushort_t* __restrict__ A, const ushort_t* __restrict__ Bw,
               const float* __restrict__ gamma, const float* __restrict__ beta,
               ushort_t* __restrict__ zbuf) {
    __shared__ ushort_t As[128 * 64];
    __shared__ ushort_t Bs[128 * 64];
    const int tid = threadIdx.x;
    const int bx = blockIdx.x, by = blockIdx.y;
    const int w = tid >> 6, lane = tid & 63;
    const int wm = w & 1, wn = w >> 1;
    const int lrow = lane & 15, lq = lane >> 4;

    const int srow = lane >> 3;
    const int scol = ((lane & 7) ^ srow) * 8;
    const ushort_t* Ag = A + (size_t)(bx * 128 + w * 32 + srow) * 2048 + scol;
    const ushort_t* Bg = Bw + (size_t)(by * 128 + w * 32 + srow) * 2048 + scol;

    floatx4 acc[4][4] = {};

    for (int k0 = 0; k0 < KSPLIT; k0 += 64) {
        const int ka = k0 - ((k0 >= 2048) ? 2048 : 0);
        const int kb = k0 - ((k0 >= 1024) ? 1024 : 0);
        __syncthreads();
#pragma unroll
        for (int n = 0; n < 4; ++n) {
            gload_lds16(Ag + (size_t)(n * 8) * 2048 + ka, &As[(w * 32 + n * 8) * 64]);
            gload_lds16(Bg + (size_t)(n * 8) * 2048 + kb, &Bs[(w * 32 + n * 8) * 64]);
        }
        __syncthreads();
#pragma unroll
        for (int kk = 0; kk < 64; kk += 32) {
            short8 af[4], bf[4];
#pragma unroll
            for (int i = 0; i < 4; ++i) {
                const int c = (((kk >> 3) + lq) ^ (lrow & 7)) * 8;
                af[i] = *(const short8*)&As[(wm * 64 + i * 16 + lrow) * 64 + c];
            }
#pragma unroll
            for (int j = 0; j < 4; ++j) {
                const int c = (((kk >> 3) + lq) ^ (lrow & 7)) * 8;
                bf[j] = *(const short8*)&Bs[(wn * 64 + j * 16 + lrow) * 64 + c];
            }
#pragma unroll
            for (int i = 0; i < 4; ++i)
#pragma unroll
                for (int j = 0; j < 4; ++j)
                    acc[i][j] = __builtin_amdgcn_mfma_f32_16x16x32_bf16(af[i], bf[j], acc[i][j], 0, 0, 0);
        }
    }

    const int rowbase = bx * 128 + wm * 64 + lq * 4;
    const int colbase = by * 128 + wn * 64 + lrow;
#pragma unroll
    for (int i = 0; i < 4; ++i)
#pragma unroll
        for (int j = 0; j < 4; ++j) {
            const int col = colbase + j * 16;
            const float gam = gamma[col], bet = beta[col];
#pragma unroll
            for (int r = 0; r < 4; ++r) {
                const int row = rowbase + i * 16 + r;
                ushort_t* zr = zbuf + (size_t)row * 2048;
                const float zn = bf2f(zr[col]) + bf2f(zr[1024 + col]);
                const float g = acc[i][j][r];
                const float sg = g / (1.0f + expf(-g));
                ushort_t hi, lo;
                split2((zn * gam + bet) * sg, hi, lo);
                zr[col] = hi;
                zr[1024 + col] = lo;
            }
        }
}

// ---------------- fallback (ws < 150 MB): round-4 proven on-the-fly-split path ----------------
template <int VAR>
__global__ __launch_bounds__(256, 2)
void gemm_split(const float* __restrict__ A,
                const ushort_t* __restrict__ B0, const ushort_t* __restrict__ B1,
                const ushort_t* __restrict__ B2,
                float* __restrict__ D0, float* __restrict__ D1, float* __restrict__ D2,
                int K) {
    __shared__ ushort_t Ah[128 * 72];
    __shared__ ushort_t Al[128 * 72];
    __shared__ ushort_t Bh[128 * 72];
    __shared__ ushort_t Bl[128 * 72];
    const int tid = threadIdx.x;
    const int bx = blockIdx.x, by = blockIdx.y;
    const ushort_t* Bt;
    float* D;
    int n0;
    bool act;
    if (VAR == 1) {
        const int wsel = by >> 3;
        Bt = (wsel == 0) ? B0 : (wsel == 1) ? B1 : B2;
        D = (wsel == 0) ? D0 : (wsel == 1) ? D1 : D2;
        n0 = (by & 7) * 128;
        act = (wsel == 0);
    } else {
        Bt = B0; D = D0; n0 = by * 128; act = true;
    }
    const int w = tid >> 6, lane = tid & 63;
    const int wm = w & 1, wn = w >> 1;
    const int lrow = lane & 15, lq = lane >> 4;
    const int srow = tid >> 1;
    const int shalf = (tid & 1) * 32;
    const float* Arow = A + (size_t)(bx * 128 + srow) * K;
    const ushort_t* Brow = Bt + (size_t)(n0 + srow) * 2048;
    floatx4 acc[4][4] = {};
    for (int k0 = 0; k0 < K; k0 += 64) {
        float4 afr[8];
        uint4 bhr[4], blr[4];
#pragma unroll
        for (int g = 0; g < 4; ++g) {
            afr[2 * g]     = *(const float4*)(Arow + k0 + shalf + g * 8);
            afr[2 * g + 1] = *(const float4*)(Arow + k0 + shalf + g * 8 + 4);
            bhr[g] = *(const uint4*)(Brow + k0 + shalf + g * 8);
            blr[g] = *(const uint4*)(Brow + 1024 + k0 + shalf + g * 8);
        }
        __syncthreads();
#pragma unroll
        for (int g = 0; g < 4; ++g) {
            ushort_t h[8], l[8];
            const float4 f0 = afr[2 * g], f1 = afr[2 * g + 1];
            split2(f0.x, h[0], l[0]); split2(f0.y, h[1], l[1]);
            split2(f0.z, h[2], l[2]); split2(f0.w, h[3], l[3]);
            split2(f1.x, h[4], l[4]); split2(f1.y, h[5], l[5]);
            split2(f1.z, h[6], l[6]); split2(f1.w, h[7], l[7]);
            uint4 hp, lp;
            hp.x = (uint_t)h[0] | ((uint_t)h[1] << 16);
            hp.y = (uint_t)h[2] | ((uint_t)h[3] << 16);
            hp.z = (uint_t)h[4] | ((uint_t)h[5] << 16);
            hp.w = (uint_t)h[6] | ((uint_t)h[7] << 16);
            lp.x = (uint_t)l[0] | ((uint_t)l[1] << 16);
            lp.y = (uint_t)l[2] | ((uint_t)l[3] << 16);
            lp.z = (uint_t)l[4] | ((uint_t)l[5] << 16);
            lp.w = (uint_t)l[6] | ((uint_t)l[7] << 16);
            *(uint4*)&Ah[srow * 72 + shalf + g * 8] = hp;
            *(uint4*)&Al[srow * 72 + shalf + g * 8] = lp;
            *(uint4*)&Bh[srow * 72 + shalf + g * 8] = bhr[g];
            *(uint4*)&Bl[srow * 72 + shalf + g * 8] = blr[g];
        }
        __syncthreads();
#pragma unroll
        for (int kk = 0; kk < 64; kk += 32) {
            short8 ah[4], bh[4], xl[4];
#pragma unroll
            for (int i = 0; i < 4; ++i)
                ah[i] = *(const short8*)&Ah[(wm * 64 + i * 16 + lrow) * 72 + kk + lq * 8];
#pragma unroll
            for (int j = 0; j < 4; ++j)
                bh[j] = *(const short8*)&Bh[(wn * 64 + j * 16 + lrow) * 72 + kk + lq * 8];
#pragma unroll
            for (int i = 0; i < 4; ++i)
#pragma unroll
                for (int j = 0; j < 4; ++j)
                    acc[i][j] = __builtin_amdgcn_mfma_f32_16x16x32_bf16(ah[i], bh[j], acc[i][j], 0, 0, 0);
#pragma unroll
            for (int i = 0; i < 4; ++i)
                xl[i] = *(const short8*)&Al[(wm * 64 + i * 16 + lrow) * 72 + kk + lq * 8];
#pragma unroll
            for (int i = 0; i < 4; ++i)
#pragma unroll
                for (int j = 0; j < 4; ++j)
                    acc[i][j] = __builtin_amdgcn_mfma_f32_16x16x32_bf16(xl[i], bh[j], acc[i][j], 0, 0, 0);
#pragma unroll
            for (int j = 0; j < 4; ++j)
                xl[j] = *(const short8*)&Bl[(wn * 64 + j * 16 + lrow) * 72 + kk + lq * 8];
#pragma unroll
            for (int i = 0; i < 4; ++i)
#pragma unroll
                for (int j = 0; j < 4; ++j)
                    acc[i][j] = __builtin_amdgcn_mfma_f32_16x16x32_bf16(ah[i], xl[j], acc[i][j], 0, 0, 0);
        }
    }
    const int rowbase = bx * 128 + wm * 64 + lq * 4;
    const int colbase = n0 + wn * 64 + lrow;
#pragma unroll
    for (int i = 0; i < 4; ++i)
#pragma unroll
        for (int j = 0; j < 4; ++j) {
            const int col = colbase + j * 16;
#pragma unroll
            for (int r = 0; r < 4; ++r) {
                const int row = rowbase + i * 16 + r;
                float val = acc[i][j][r];
                if (act) val = (val > 0.0f) ? (val + 1.0f) : (expm1f(val) + 1.0f);
                D[(size_t)row * HDIM + col] = val;
            }
        }
}

__global__ __launch_bounds__(256)
void token_f32(const float* __restrict__ qd, const float* __restrict__ vd,
               const float* __restrict__ gd, float* kz,
               const float* __restrict__ ksum,
               const float* __restrict__ gamma, const float* __restrict__ beta,
               int chunk_base) {
    const int tl = blockIdx.x;
    const int t = chunk_base + tl;
    const int b = t >> 13;
    const int tid = threadIdx.x;
    const float4 q = ((const float4*)(qd + (size_t)tl * HDIM))[tid];
    const float4 k = ((const float4*)(kz + (size_t)t * HDIM))[tid];
    const float4 v = ((const float4*)(vd + (size_t)tl * HDIM))[tid];
    const float4 ks = ((const float4*)(ksum + (size_t)b * HDIM))[tid];
    float qk = q.x * k.x + q.y * k.y + q.z * k.z + q.w * k.w;
    float nm = q.x * ks.x + q.y * ks.y + q.z * ks.z + q.w * ks.w;
#pragma unroll
    for (int off = 1; off < 16; off <<= 1) {
        qk += __shfl_xor(qk, off, 64);
        nm += __shfl_xor(nm, off, 64);
    }
    const float sc = qk / (nm + 1e-6f);
    float z[4] = {v.x * sc, v.y * sc, v.z * sc, v.w * sc};
    __shared__ float red[8];
    const int wv = tid >> 6, lane = tid & 63;
    float s1 = z[0] + z[1] + z[2] + z[3];
#pragma unroll
    for (int off = 1; off < 64; off <<= 1) s1 += __shfl_xor(s1, off, 64);
    if (lane == 0) red[wv] = s1;
    __syncthreads();
    const float mu = (red[0] + red[1] + red[2] + red[3]) * (1.0f / 1024.0f);
    float d[4] = {z[0] - mu, z[1] - mu, z[2] - mu, z[3] - mu};
    float s2 = d[0] * d[0] + d[1] * d[1] + d[2] * d[2] + d[3] * d[3];
#pragma unroll
    for (int off = 1; off < 64; off <<= 1) s2 += __shfl_xor(s2, off, 64);
    __syncthreads();
    if (lane == 0) red[4 + wv] = s2;
    __syncthreads();
    const float var = (red[4] + red[5] + red[6] + red[7]) * (1.0f / 1024.0f);
    const float rstd = rsqrtf(var + 1e-5f);
    const float4 gm = ((const float4*)gamma)[tid];
    const float4 bt = ((const float4*)beta)[tid];
    const float4 g = ((const float4*)(gd + (size_t)tl * HDIM))[tid];
    const float gv[4] = {g.x, g.y, g.z, g.w};
    const float gmv[4] = {gm.x, gm.y, gm.z, gm.w};
    const float btv[4] = {bt.x, bt.y, bt.z, bt.w};
    ushort_t hi[4], lo[4];
#pragma unroll
    for (int c = 0; c < 4; ++c) {
        const float zn = d[c] * rstd * gmv[c] + btv[c];
        const float sg = gv[c] / (1.0f + expf(-gv[c]));
        split2(zn * sg, hi[c], lo[c]);
    }
    ushort_t* zrow = (ushort_t*)(kz + (size_t)t * HDIM);
    uint2 hp, lp;
    hp.x = (uint_t)hi[0] | ((uint_t)hi[1] << 16);
    hp.y = (uint_t)hi[2] | ((uint_t)hi[3] << 16);
    lp.x = (uint_t)lo[0] | ((uint_t)lo[1] << 16);
    lp.y = (uint_t)lo[2] | ((uint_t)lo[3] << 16);
    *(uint2*)(zrow + tid * 4) = hp;
    *(uint2*)(zrow + 1024 + tid * 4) = lp;
}

// ---------------- launcher ----------------
extern "C" void kernel_launch(void* const* d_in, const int* in_sizes, int n_in,
                              void* d_out, int out_size, void* d_ws, size_t ws_size,
                              hipStream_t stream) {
    const float* hidden = (const float*)d_in[0];
    const float* Wq = (const float*)d_in[1];
    const float* Wk = (const float*)d_in[2];
    const float* Wv = (const float*)d_in[3];
    const float* Wg = (const float*)d_in[4];
    const float* Wo = (const float*)d_in[5];
    const float* gamma = (const float*)d_in[6];
    const float* beta = (const float*)d_in[7];

    char* w = (char*)d_ws;
    float* kb = (float*)w;            w += (size_t)67108864;   // k -> v -> zn -> Zs
    ushort_t* WT2 = (ushort_t*)w;     w += (size_t)20971520;   // 5 weights split [n][2048]
    float* partial = (float*)w;       w += (size_t)1048576;
    float* ksum = (float*)w;          w += (size_t)8192;
    float* scbuf = (float*)w;         w += (size_t)1048576;    // sc[t][16]
    const size_t base = (size_t)(w - (char*)d_ws);             // ~90.2 MB

    ushort_t* Wk2 = WT2;
    ushort_t* Wq2 = WT2 + (size_t)1 * HDIM * 2048;
    ushort_t* Wv2 = WT2 + (size_t)2 * HDIM * 2048;
    ushort_t* Wg2 = WT2 + (size_t)3 * HDIM * 2048;
    ushort_t* Wo2 = WT2 + (size_t)4 * HDIM * 2048;

    split_w<<<dim3(32, 32, 5), 256, 0, stream>>>(Wk, Wq, Wv, Wg, Wo, WT2);

    if (ws_size >= base + 67108864ull) {  // main path: ~150 MB (measured ws >= ~173 MB)
        ushort_t* Hs = (ushort_t*)w;
        split_hidden<<<dim3(T_TOK), 256, 0, stream>>>(hidden, Hs);
        // K: kb = elu(h@Wk)+1
        gemm_swz<0><<<dim3(128, 8), 256, 0, stream>>>(Hs, Wk2, kb, nullptr, nullptr,
                                                      nullptr, nullptr);
        ksum_partial<<<dim3(256), 256, 0, stream>>>(kb, partial);
        ksum_reduce<<<dim3(4, 2), 256, 0, stream>>>(partial, ksum);
        // Q: epilogue-reduce sc[t][h]
        gemm_swz<1><<<dim3(128, 8), 256, 0, stream>>>(Hs, Wq2, nullptr, kb, ksum,
                                                      scbuf, nullptr);
        // V: v over kb (k dead)
        gemm_swz<2><<<dim3(128, 8), 256, 0, stream>>>(Hs, Wv2, kb, nullptr, nullptr,
                                                      nullptr, nullptr);
        // token-lite: z=v*sc, LN -> zn hi|lo in place
        token_lite<<<dim3(T_TOK), 256, 0, stream>>>(kb, scbuf);
        // G: gate (zn*gamma+beta)*silu(g) in place
        gemm_gate<0><<<dim3(128, 8), 256, 0, stream>>>(Hs, Wg2, gamma, beta,
                                                       (ushort_t*)kb);
        // O: out = Zs @ Wo
        gemm_swz<2><<<dim3(128, 8), 256, 0, stream>>>((const ushort_t*)kb, Wo2,
                                                      (float*)d_out, nullptr, nullptr,
                                                      nullptr, nullptr);
    } else {  // fallback: round-4 proven path (~110 MB)
        const int C = 2048;
        float* qc = (float*)w;
        float* vc = qc + (size_t)C * HDIM;
        float* gc = vc + (size_t)C * HDIM;
        gemm_split<0><<<dim3(128, 8), 256, 0, stream>>>(hidden, Wk2, nullptr, nullptr,
                                                        kb, nullptr, nullptr, HDIM);
        ksum_partial<<<dim3(256), 256, 0, stream>>>(kb, partial);
        ksum_reduce<<<dim3(4, 2), 256, 0, stream>>>(partial, ksum);
        for (int c = 0; c < 8; ++c) {
            const float* Ac = hidden + (size_t)c * C * HDIM;
            gemm_split<1><<<dim3(C / 128, 24), 256, 0, stream>>>(Ac, Wq2, Wv2, Wg2,
                                                                 qc, vc, gc, HDIM);
            token_f32<<<dim3(C), 256, 0, stream>>>(qc, vc, gc, kb, ksum,
                                                   gamma, beta, c * C);
        }
        gemm_swz<2><<<dim3(128, 8), 256, 0, stream>>>((const ushort_t*)kb, Wo2,
                                                      (float*)d_out, nullptr, nullptr,
                                                      nullptr, nullptr);
    }
}